// Round 15
// baseline (67.656 us; speedup 1.0000x reference)
//
#include <hip/hip_runtime.h>

// Problem constants
#define BB   8
#define CIN  128
#define COUT 128
#define KS   7
#define HH   32
#define WWID 32
#define HW   1024
#define NG   8     // dynamic-weight groups
#define GC   16    // channels per group
#define MROWS 768  // 256 t-rows + 512 v-rows
#define TROWS 256
#define VROWS 512
#define KDIM 512
#define WMAP_O 392  // 49*8
#define WMAP_OP 448 // padded to 7*64
#define C2K  64

#define AS1 __attribute__((address_space(1)))
#define AS3 __attribute__((address_space(3)))

typedef __attribute__((ext_vector_type(8))) short bf16x8;
typedef __attribute__((ext_vector_type(4))) float f32x4;

__device__ __forceinline__ short f2bf(float f) {
    unsigned u = __builtin_bit_cast(unsigned, f);
    u += 0x7fff + ((u >> 16) & 1);   // RNE
    return (short)(u >> 16);
}
__device__ __forceinline__ float bf2f(unsigned short u) {
    unsigned v = (unsigned)u << 16;
    return __builtin_bit_cast(float, v);
}

// ---------------------------------------------------------------- fused prep:
// blocks 0..1023:    transpose x -> XT bf16 [b][hw][c]
// blocks 1024..2559: lift weights -> Wb bf16 [768][512]
// blocks 2560..2671: c2 pad -> c2wb bf16 [448][64], c2bp f32 [448]
// block  2672:       zero gnstat (512 groups x {s, sq})
__global__ __launch_bounds__(256) void prep_kernel(
    const float* __restrict__ x, const float* __restrict__ v_w,
    const float* __restrict__ c1_w, const float* __restrict__ c2_w,
    const float* __restrict__ c2_b,
    short* __restrict__ XT, short* __restrict__ Wb,
    short* __restrict__ c2wb, float* __restrict__ c2bp,
    float* __restrict__ gnstat)
{
    __shared__ short t[64][66];
    int bx = blockIdx.x, tid = threadIdx.x;
    if (bx < 1024) {
        int b = bx >> 7, c0 = ((bx >> 4) & 7) * 64, n0 = (bx & 15) * 64;
        const float* xb = x + ((size_t)b * KDIM + c0) * HW + n0;
        #pragma unroll
        for (int l = 0; l < 16; ++l) {
            int flat = l * 256 + tid;
            int row = flat >> 6, col = flat & 63;
            t[col][row] = f2bf(xb[(size_t)row * HW + col]);
        }
        __syncthreads();
        short* xt = XT + ((size_t)b * HW + n0) * KDIM + c0;
        #pragma unroll
        for (int l = 0; l < 8; ++l) {
            int u = l * 256 + tid;
            int nrow = u >> 5, cp = (u & 31) * 2;
            short2 v = make_short2(t[nrow][cp], t[nrow][cp + 1]);
            *(short2*)(xt + (size_t)nrow * KDIM + cp) = v;
        }
    } else if (bx < 2560) {
        int idx = (bx - 1024) * 256 + tid;     // < 768*512 exactly
        int row = idx >> 9, col = idx & 511;
        int i = col >> 2, s = col & 3;
        float val;
        if (row < 256) {
            int o = row >> 2, r = row & 3;
            val = c1_w[(o * CIN + i) * 4 + ((s - r) & 3)];
        } else {
            int ro = row - 256;
            int o = ro >> 2, r = ro & 3;
            val = v_w[(o * CIN + i) * 4 + ((s - r) & 3)];
        }
        Wb[idx] = f2bf(val);
    } else if (bx < 2672) {
        int idx = (bx - 2560) * 256 + tid;     // < 448*64 exactly
        int o = idx >> 6, k = idx & 63;
        c2wb[idx] = f2bf(o < WMAP_O ? c2_w[o * C2K + k] : 0.f);
        if (idx < WMAP_OP)
            c2bp[idx] = idx < WMAP_O ? c2_b[idx] : 0.f;
    } else {
        *(float4*)(gnstat + tid * 4) = make_float4(0.f, 0.f, 0.f, 0.f);
    }
}

// ---------------------------------------------------------------- MFMA GEMM (2-phase dbuf, R11 config):
// tvb[b] = bf16( Wb @ X[b] ), + GN partial stats
#define GBM 64
#define GBN 128
#define GBK 64
__global__ __launch_bounds__(256) void gemm_mfma_kernel(
    const short* __restrict__ Wb, const short* __restrict__ XT,
    short* __restrict__ tvb, float* __restrict__ gnstat)
{
    __shared__ short As[2][GBM * GBK];   // 2 x  8 KB
    __shared__ short Bs[2][GBN * GBK];   // 2 x 16 KB
    int b  = blockIdx.z;
    int m0 = blockIdx.y * GBM;
    int n0 = blockIdx.x * GBN;
    int tid = threadIdx.x;
    int lane = tid & 63, wv = tid >> 6;
    int wm = wv & 1, wn = wv >> 1;          // wave tile: 32 rows x 64 cols
    int rl = lane & 15, kg = lane >> 4;
    const short* Ab = Wb + (size_t)m0 * KDIM;
    const short* Bb = XT + ((size_t)b * HW + n0) * KDIM;
    f32x4 acc[2][4] = {};

#define GEMM_STAGE(buf, k0)                                                              \
    do {                                                                                 \
        _Pragma("unroll")                                                                \
        for (int l = 0; l < 2; ++l) {                                                    \
            int c = l * 256 + tid;                                                       \
            int row = c >> 3, kc = c & 7;                                                \
            int kcs = kc ^ (row & 7);                                                    \
            __builtin_amdgcn_global_load_lds(                                            \
                (const AS1 void*)(Ab + (size_t)row * KDIM + (k0) + kcs * 8),             \
                (AS3 void*)(As[buf] + (l * 256 + wv * 64) * 8), 16, 0, 0);               \
        }                                                                                \
        _Pragma("unroll")                                                                \
        for (int l = 0; l < 4; ++l) {                                                    \
            int c = l * 256 + tid;                                                       \
            int row = c >> 3, kc = c & 7;                                                \
            int kcs = kc ^ (row & 7);                                                    \
            __builtin_amdgcn_global_load_lds(                                            \
                (const AS1 void*)(Bb + (size_t)row * KDIM + (k0) + kcs * 8),             \
                (AS3 void*)(Bs[buf] + (l * 256 + wv * 64) * 8), 16, 0, 0);               \
        }                                                                                \
    } while (0)

    GEMM_STAGE(0, 0);
    __syncthreads();
    for (int t = 0; t < KDIM / GBK; ++t) {
        int cur = t & 1;
        if (t < KDIM / GBK - 1) GEMM_STAGE(cur ^ 1, (t + 1) * GBK);
        #pragma unroll
        for (int ks = 0; ks < 2; ++ks) {
            bf16x8 af[2], bfr[4];
            #pragma unroll
            for (int mf = 0; mf < 2; ++mf) {
                int row = wm * 32 + mf * 16 + rl;
                af[mf] = *(const bf16x8*)(As[cur] + row * GBK + ((ks * 4 + kg) ^ (row & 7)) * 8);
            }
            #pragma unroll
            for (int nf = 0; nf < 4; ++nf) {
                int row = wn * 64 + nf * 16 + rl;
                bfr[nf] = *(const bf16x8*)(Bs[cur] + row * GBK + ((ks * 4 + kg) ^ (row & 7)) * 8);
            }
            #pragma unroll
            for (int mf = 0; mf < 2; ++mf)
                #pragma unroll
                for (int nf = 0; nf < 4; ++nf)
                    acc[mf][nf] = __builtin_amdgcn_mfma_f32_16x16x32_bf16(af[mf], bfr[nf], acc[mf][nf], 0, 0, 0);
        }
        __syncthreads();
    }
#undef GEMM_STAGE

    short* Cb = tvb + (size_t)b * MROWS * HW;
    #pragma unroll
    for (int mf = 0; mf < 2; ++mf) {
        int rowb = m0 + wm * 32 + mf * 16 + kg * 4;
        #pragma unroll
        for (int nf = 0; nf < 4; ++nf) {
            int col = n0 + wn * 64 + nf * 16 + rl;
            #pragma unroll
            for (int i = 0; i < 4; ++i)
                Cb[(size_t)(rowb + i) * HW + col] = f2bf(acc[mf][nf][i]);
        }
    }

    // GN partial stats for t rows: each (wave,mf) covers one 4-row group x 64 cols
    if (m0 < TROWS) {
        #pragma unroll
        for (int mf = 0; mf < 2; ++mf) {
            float s = 0.f, sq = 0.f;
            #pragma unroll
            for (int nf = 0; nf < 4; ++nf)
                #pragma unroll
                for (int i = 0; i < 4; ++i) {
                    float v = acc[mf][nf][i];
                    s += v; sq += v * v;
                }
            #pragma unroll
            for (int m = 1; m <= 8; m <<= 1) {
                s  += __shfl_xor(s, m);
                sq += __shfl_xor(sq, m);
            }
            if (rl == 0) {
                int grp = (m0 + wm * 32 + mf * 16 + kg * 4) >> 2;
                atomicAdd(&gnstat[(b * 64 + grp) * 2],     s);
                atomicAdd(&gnstat[(b * 64 + grp) * 2 + 1], sq);
            }
        }
    }
}

// ---------------------------------------------------------------- wmap v4: fused normalize+transpose + MFMA
// Per block: Bs[64 hw][64 c] = bf16(relu(tvb_t * sc + sh)) built from tvb in-LDS;
// wmapB[b4r][o][n0..n0+63] = bf16( c2bp[o] + c2wb[o][:] @ Bs^T )
__global__ __launch_bounds__(256) void wmap4_kernel(
    const short* __restrict__ c2wb, const short* __restrict__ tvb,
    const float* __restrict__ gnstat, const float* __restrict__ gn_g,
    const float* __restrict__ gn_b, const float* __restrict__ c2bp,
    short* __restrict__ wmapB)
{
    __shared__ short smem[4096 + 4096 + 4608];  // As[64][64] | Bs[64][64] | T[64][72]
    __shared__ float sc[64], sh[64];
    short* As = smem;            // 4096 shorts
    short* Bs = smem + 4096;     // 4096 shorts
    short* T  = smem + 8192;     // 4608 shorts, pitch 72
    short* Ps = smem;            // [64][68] = 4352 shorts, aliases As..Bs after MFMA

    int n0  = blockIdx.x * 64;
    int m0  = blockIdx.y * 64;
    int b4r = blockIdx.z;
    int b = b4r >> 2, r = b4r & 3;
    int tid = threadIdx.x;
    int lane = tid & 63, wv = tid >> 6;
    int wm = wv & 1, wn = (wv >> 1) & 1;    // wave tile 32x32
    int rl = lane & 15, kg = lane >> 4;

    // stage A: c2wb rows m0..m0+63, swizzled source (512 chunks)
    #pragma unroll
    for (int l = 0; l < 2; ++l) {
        int c = l * 256 + tid;
        int row = c >> 3, kc = c & 7;
        int kcs = kc ^ (row & 7);
        __builtin_amdgcn_global_load_lds(
            (const AS1 void*)(c2wb + (size_t)(m0 + row) * C2K + kcs * 8),
            (AS3 void*)(As + (l * 256 + wv * 64) * 8), 16, 0, 0);
    }
    // scale factors (identical formula to old tkn2)
    if (tid < 64) {
        float s   = gnstat[(b * 64 + tid) * 2];
        float sq  = gnstat[(b * 64 + tid) * 2 + 1];
        float mu  = s * (1.f / 4096.f);
        float var = sq * (1.f / 4096.f) - mu * mu;
        float inv = rsqrtf(var + 1e-5f);
        int ch = tid * 4 + r;
        float g = gn_g[ch], bb2 = gn_b[ch];
        sc[tid] = inv * g;
        sh[tid] = bb2 - mu * inv * g;
    }
    // stage T: raw t rows, T[c][hw_l], 512 chunks coalesced
    #pragma unroll
    for (int l = 0; l < 2; ++l) {
        int cid = l * 256 + tid;
        int c = cid >> 3, ch = cid & 7;
        bf16x8 v = *(const bf16x8*)(tvb + ((size_t)b * MROWS + c * 4 + r) * HW + n0 + ch * 8);
        *(bf16x8*)(T + c * 72 + ch * 8) = v;
    }
    __syncthreads();

    // build Bs[hw][c] normalized, swizzled: chunk (row, kc) -> Bs[row*64 + (kc^(row&7))*8]
    #pragma unroll
    for (int l = 0; l < 2; ++l) {
        int cid = l * 256 + tid;
        int row = cid >> 3, kc = cid & 7;
        int kcs = kc ^ (row & 7);
        bf16x8 v;
        #pragma unroll
        for (int j = 0; j < 8; ++j) {
            int c = kc * 8 + j;
            float f = bf2f((unsigned short)T[c * 72 + row]);
            f = fmaxf(f * sc[c] + sh[c], 0.f);
            v[j] = f2bf(f);
        }
        *(bf16x8*)(Bs + row * 64 + kcs * 8) = v;
    }
    __syncthreads();

    f32x4 acc[2][2] = {};
    #pragma unroll
    for (int ks = 0; ks < 2; ++ks) {
        bf16x8 af[2], bfr[2];
        #pragma unroll
        for (int mf = 0; mf < 2; ++mf) {
            int row = wm * 32 + mf * 16 + rl;
            af[mf] = *(const bf16x8*)(As + row * 64 + ((ks * 4 + kg) ^ (row & 7)) * 8);
        }
        #pragma unroll
        for (int nf = 0; nf < 2; ++nf) {
            int row = wn * 32 + nf * 16 + rl;
            bfr[nf] = *(const bf16x8*)(Bs + row * 64 + ((ks * 4 + kg) ^ (row & 7)) * 8);
        }
        #pragma unroll
        for (int mf = 0; mf < 2; ++mf)
            #pragma unroll
            for (int nf = 0; nf < 2; ++nf)
                acc[mf][nf] = __builtin_amdgcn_mfma_f32_16x16x32_bf16(af[mf], bfr[nf], acc[mf][nf], 0, 0, 0);
    }
    __syncthreads();   // frag reads done -> reuse As/Bs region as Ps

    // repack: bias + bf16 into LDS [64][68]
    #pragma unroll
    for (int mf = 0; mf < 2; ++mf) {
        int rowl = wm * 32 + mf * 16 + kg * 4;
        float bi[4];
        #pragma unroll
        for (int i = 0; i < 4; ++i) bi[i] = c2bp[m0 + rowl + i];
        #pragma unroll
        for (int nf = 0; nf < 2; ++nf) {
            int col = wn * 32 + nf * 16 + rl;
            #pragma unroll
            for (int i = 0; i < 4; ++i)
                Ps[(rowl + i) * 68 + col] = f2bf(acc[mf][nf][i] + bi[i]);
        }
    }
    __syncthreads();

    // coalesced store: thread -> row = tid>>2, 2 x 16B segments, skip pad rows
    int row = tid >> 2, segl = tid & 3;
    if (m0 + row < WMAP_O) {
        short* dst = wmapB + (size_t)b4r * WMAP_OP * HW + (size_t)(m0 + row) * HW + n0;
        #pragma unroll
        for (int s2 = 0; s2 < 2; ++s2) {
            int col = segl * 8 + s2 * 32;
            *(bf16x8*)(dst + col) = *(const bf16x8*)(Ps + row * 68 + col);
        }
    }
}

// ---------------------------------------------------------------- aggregation v6
// grid: (256 bgr, 4 h-strips, 2 c-halves); block: 8 ch x 8 h x 32 w
__global__ __launch_bounds__(256, 5) void agg6_kernel(
    const short* __restrict__ tvb, const short* __restrict__ wmapB,
    float* __restrict__ out)
{
    __shared__ float vt[8][15][44];   // 21.1 KB
    int bx = blockIdx.x;              // b*32 + g*4 + r
    int b = bx >> 5;
    int g = (bx >> 2) & 7;
    int r = bx & 3;
    int h0   = blockIdx.y * 8;
    int half = blockIdx.z;
    int tid  = threadIdx.x;
    int w0q = tid & 7, hb = (tid >> 3) & 1, cc4 = (tid >> 4) & 3, cq = tid >> 6;
    int hl = cq * 2 + hb;             // local h 0..7
    int h = h0 + hl, w0 = w0q * 4;

    int A, Bc, Cc;
    if      (r == 0) { A = 0;  Bc = 7;  Cc = 1;  }
    else if (r == 1) { A = 6;  Bc = -1; Cc = 7;  }
    else if (r == 2) { A = 48; Bc = -7; Cc = -1; }
    else             { A = 42; Bc = 1;  Cc = -7; }

    const short* vpb = tvb + ((size_t)b * MROWS + TROWS) * HW;
    for (int e = tid; e < 8 * 15 * 3; e += 256) {
        int cc  = e / 45;
        int rem = e - cc * 45;
        int row = rem / 3, q = rem - row * 3;
        int col = (q == 0) ? 0 : (36 + (q - 1) * 4);
        *(float4*)(&vt[cc][row][col]) = make_float4(0.f, 0.f, 0.f, 0.f);
    }
    for (int f = tid; f < 8 * 15 * 8; f += 256) {
        int cc  = f / 120;
        int rem = f - cc * 120;
        int row = rem >> 3, q = rem & 7;
        int gh = h0 - 3 + row;
        float4 v4 = make_float4(0.f, 0.f, 0.f, 0.f);
        if (gh >= 0 && gh < HH) {
            int ch = (g * GC + half * 8 + cc) * 4 + r;
            ushort4 u = *(const ushort4*)(vpb + (size_t)ch * HW + gh * WWID + q * 4);
            v4 = make_float4(bf2f(u.x), bf2f(u.y), bf2f(u.z), bf2f(u.w));
        }
        *(float4*)(&vt[cc][row][4 + q * 4]) = v4;
    }
    __syncthreads();

    const short* wmb = wmapB + ((size_t)(b * 4 + r) * WMAP_OP + g * 49) * HW + h * WWID + w0;
    float acc[2][4] = {};
    #pragma unroll
    for (int di = 0; di < 7; ++di) {
        float wrf[7][4];
        #pragma unroll
        for (int dj = 0; dj < 7; ++dj) {
            int porig = A + Bc * di + Cc * dj;
            ushort4 wv = *(const ushort4*)(wmb + (size_t)porig * HW);
            wrf[dj][0] = bf2f(wv.x); wrf[dj][1] = bf2f(wv.y);
            wrf[dj][2] = bf2f(wv.z); wrf[dj][3] = bf2f(wv.w);
        }
        #pragma unroll
        for (int c2 = 0; c2 < 2; ++c2) {
            int hc = cc4 * 2 + c2;
            const float* rp = &vt[hc][hl + di][w0];
            float4 q0 = *(const float4*)(rp);
            float4 q1 = *(const float4*)(rp + 4);
            float4 q2 = *(const float4*)(rp + 8);
            float win[12] = {q0.x, q0.y, q0.z, q0.w,
                             q1.x, q1.y, q1.z, q1.w,
                             q2.x, q2.y, q2.z, q2.w};
            #pragma unroll
            for (int dj = 0; dj < 7; ++dj)
                #pragma unroll
                for (int px = 0; px < 4; ++px)
                    acc[c2][px] += wrf[dj][px] * win[px + dj + 1];
        }
    }
    #pragma unroll
    for (int c2 = 0; c2 < 2; ++c2) {
        int ch = (g * GC + half * 8 + cc4 * 2 + c2) * 4 + r;
        float4 o4 = make_float4(acc[c2][0], acc[c2][1], acc[c2][2], acc[c2][3]);
        *(float4*)(out + ((size_t)b * 512 + ch) * HW + h * WWID + w0) = o4;
    }
}

// ---------------------------------------------------------------- launch
extern "C" void kernel_launch(void* const* d_in, const int* in_sizes, int n_in,
                              void* d_out, int out_size, void* d_ws, size_t ws_size,
                              hipStream_t stream)
{
    const float* x    = (const float*)d_in[0];
    const float* v_w  = (const float*)d_in[1];
    const float* c1_w = (const float*)d_in[2];
    const float* gn_g = (const float*)d_in[3];
    const float* gn_b = (const float*)d_in[4];
    const float* c2_w = (const float*)d_in[5];
    const float* c2_b = (const float*)d_in[6];
    float* out = (float*)d_out;

    // workspace layout (XT aliases wmapB; XT dead before wmapB written)
    char* p = (char*)d_ws;
    short* Wb     = (short*)p;           p += (size_t)MROWS * KDIM * 2;        //  0.79 MB
    short* tvb    = (short*)p;           p += (size_t)BB * MROWS * HW * 2;     // 12.6 MB
    short* wmapB  = (short*)p;           p += (size_t)32 * WMAP_OP * HW * 2;   // 29.4 MB
    short* XT     = (short*)wmapB;                                             //  8.4 MB (aliased)
    short* c2wb   = (short*)p;           p += (size_t)WMAP_OP * C2K * 2;       // 57 KB
    float* c2bp   = (float*)p;           p += (size_t)WMAP_OP * 4;
    float* gnstat = (float*)p;           p += (size_t)512 * 2 * 4;             //  4 KB

    prep_kernel     <<<2673, 256, 0, stream>>>(x, v_w, c1_w, c2_w, c2_b, XT, Wb, c2wb, c2bp, gnstat);
    gemm_mfma_kernel<<<dim3(HW / GBN, MROWS / GBM, BB), 256, 0, stream>>>(Wb, XT, tvb, gnstat);
    wmap4_kernel    <<<dim3(16, 7, 32), 256, 0, stream>>>(c2wb, tvb, gnstat, gn_g, gn_b, c2bp, wmapB);
    agg6_kernel     <<<dim3(BB * NG * 4, 4, 2), 256, 0, stream>>>(tvb, wmapB, out);
}

// Round 16
// 61.273 us; speedup vs baseline: 1.1042x; 1.1042x over previous
//
#include <hip/hip_runtime.h>

// Problem constants
#define BB   8
#define CIN  128
#define COUT 128
#define KS   7
#define HH   32
#define WWID 32
#define HW   1024
#define NG   8     // dynamic-weight groups
#define GC   16    // channels per group
#define MROWS 768  // 256 t-rows + 512 v-rows
#define TROWS 256
#define VROWS 512
#define KDIM 512
#define WMAP_O 392  // 49*8
#define WMAP_OP 448 // padded to 7*64
#define C2K  64

#define AS1 __attribute__((address_space(1)))
#define AS3 __attribute__((address_space(3)))

typedef __attribute__((ext_vector_type(8))) short bf16x8;
typedef __attribute__((ext_vector_type(4))) float f32x4;

__device__ __forceinline__ short f2bf(float f) {
    unsigned u = __builtin_bit_cast(unsigned, f);
    u += 0x7fff + ((u >> 16) & 1);   // RNE
    return (short)(u >> 16);
}
__device__ __forceinline__ float bf2f(unsigned short u) {
    unsigned v = (unsigned)u << 16;
    return __builtin_bit_cast(float, v);
}

// ---------------------------------------------------------------- fused prep:
// blocks 0..1023:    transpose x -> XT bf16 [b][hw][c]
// blocks 1024..2559: lift weights -> Wb bf16 [768][512]
// blocks 2560..2671: c2 pad -> c2wb bf16 [448][64], c2bp f32 [448]
// block  2672:       zero gnstat (512 groups x {s, sq})
__global__ __launch_bounds__(256) void prep_kernel(
    const float* __restrict__ x, const float* __restrict__ v_w,
    const float* __restrict__ c1_w, const float* __restrict__ c2_w,
    const float* __restrict__ c2_b,
    short* __restrict__ XT, short* __restrict__ Wb,
    short* __restrict__ c2wb, float* __restrict__ c2bp,
    float* __restrict__ gnstat)
{
    __shared__ short t[64][66];
    int bx = blockIdx.x, tid = threadIdx.x;
    if (bx < 1024) {
        int b = bx >> 7, c0 = ((bx >> 4) & 7) * 64, n0 = (bx & 15) * 64;
        const float* xb = x + ((size_t)b * KDIM + c0) * HW + n0;
        #pragma unroll
        for (int l = 0; l < 16; ++l) {
            int flat = l * 256 + tid;
            int row = flat >> 6, col = flat & 63;
            t[col][row] = f2bf(xb[(size_t)row * HW + col]);
        }
        __syncthreads();
        short* xt = XT + ((size_t)b * HW + n0) * KDIM + c0;
        #pragma unroll
        for (int l = 0; l < 8; ++l) {
            int u = l * 256 + tid;
            int nrow = u >> 5, cp = (u & 31) * 2;
            short2 v = make_short2(t[nrow][cp], t[nrow][cp + 1]);
            *(short2*)(xt + (size_t)nrow * KDIM + cp) = v;
        }
    } else if (bx < 2560) {
        int idx = (bx - 1024) * 256 + tid;     // < 768*512 exactly
        int row = idx >> 9, col = idx & 511;
        int i = col >> 2, s = col & 3;
        float val;
        if (row < 256) {
            int o = row >> 2, r = row & 3;
            val = c1_w[(o * CIN + i) * 4 + ((s - r) & 3)];
        } else {
            int ro = row - 256;
            int o = ro >> 2, r = ro & 3;
            val = v_w[(o * CIN + i) * 4 + ((s - r) & 3)];
        }
        Wb[idx] = f2bf(val);
    } else if (bx < 2672) {
        int idx = (bx - 2560) * 256 + tid;     // < 448*64 exactly
        int o = idx >> 6, k = idx & 63;
        c2wb[idx] = f2bf(o < WMAP_O ? c2_w[o * C2K + k] : 0.f);
        if (idx < WMAP_OP)
            c2bp[idx] = idx < WMAP_O ? c2_b[idx] : 0.f;
    } else {
        *(float4*)(gnstat + tid * 4) = make_float4(0.f, 0.f, 0.f, 0.f);
    }
}

// ---------------------------------------------------------------- MFMA GEMM (2-phase dbuf):
// tvb[b] = bf16( Wb @ X[b] ), + GN partial stats
#define GBM 64
#define GBN 128
#define GBK 64
__global__ __launch_bounds__(256) void gemm_mfma_kernel(
    const short* __restrict__ Wb, const short* __restrict__ XT,
    short* __restrict__ tvb, float* __restrict__ gnstat)
{
    __shared__ short As[2][GBM * GBK];   // 2 x  8 KB
    __shared__ short Bs[2][GBN * GBK];   // 2 x 16 KB
    int b  = blockIdx.z;
    int m0 = blockIdx.y * GBM;
    int n0 = blockIdx.x * GBN;
    int tid = threadIdx.x;
    int lane = tid & 63, wv = tid >> 6;
    int wm = wv & 1, wn = wv >> 1;          // wave tile: 32 rows x 64 cols
    int rl = lane & 15, kg = lane >> 4;
    const short* Ab = Wb + (size_t)m0 * KDIM;
    const short* Bb = XT + ((size_t)b * HW + n0) * KDIM;
    f32x4 acc[2][4] = {};

#define GEMM_STAGE(buf, k0)                                                              \
    do {                                                                                 \
        _Pragma("unroll")                                                                \
        for (int l = 0; l < 2; ++l) {                                                    \
            int c = l * 256 + tid;                                                       \
            int row = c >> 3, kc = c & 7;                                                \
            int kcs = kc ^ (row & 7);                                                    \
            __builtin_amdgcn_global_load_lds(                                            \
                (const AS1 void*)(Ab + (size_t)row * KDIM + (k0) + kcs * 8),             \
                (AS3 void*)(As[buf] + (l * 256 + wv * 64) * 8), 16, 0, 0);               \
        }                                                                                \
        _Pragma("unroll")                                                                \
        for (int l = 0; l < 4; ++l) {                                                    \
            int c = l * 256 + tid;                                                       \
            int row = c >> 3, kc = c & 7;                                                \
            int kcs = kc ^ (row & 7);                                                    \
            __builtin_amdgcn_global_load_lds(                                            \
                (const AS1 void*)(Bb + (size_t)row * KDIM + (k0) + kcs * 8),             \
                (AS3 void*)(Bs[buf] + (l * 256 + wv * 64) * 8), 16, 0, 0);               \
        }                                                                                \
    } while (0)

    GEMM_STAGE(0, 0);
    __syncthreads();
    for (int t = 0; t < KDIM / GBK; ++t) {
        int cur = t & 1;
        if (t < KDIM / GBK - 1) GEMM_STAGE(cur ^ 1, (t + 1) * GBK);
        #pragma unroll
        for (int ks = 0; ks < 2; ++ks) {
            bf16x8 af[2], bfr[4];
            #pragma unroll
            for (int mf = 0; mf < 2; ++mf) {
                int row = wm * 32 + mf * 16 + rl;
                af[mf] = *(const bf16x8*)(As[cur] + row * GBK + ((ks * 4 + kg) ^ (row & 7)) * 8);
            }
            #pragma unroll
            for (int nf = 0; nf < 4; ++nf) {
                int row = wn * 64 + nf * 16 + rl;
                bfr[nf] = *(const bf16x8*)(Bs[cur] + row * GBK + ((ks * 4 + kg) ^ (row & 7)) * 8);
            }
            #pragma unroll
            for (int mf = 0; mf < 2; ++mf)
                #pragma unroll
                for (int nf = 0; nf < 4; ++nf)
                    acc[mf][nf] = __builtin_amdgcn_mfma_f32_16x16x32_bf16(af[mf], bfr[nf], acc[mf][nf], 0, 0, 0);
        }
        __syncthreads();
    }
#undef GEMM_STAGE

    short* Cb = tvb + (size_t)b * MROWS * HW;
    #pragma unroll
    for (int mf = 0; mf < 2; ++mf) {
        int rowb = m0 + wm * 32 + mf * 16 + kg * 4;
        #pragma unroll
        for (int nf = 0; nf < 4; ++nf) {
            int col = n0 + wn * 64 + nf * 16 + rl;
            #pragma unroll
            for (int i = 0; i < 4; ++i)
                Cb[(size_t)(rowb + i) * HW + col] = f2bf(acc[mf][nf][i]);
        }
    }

    // GN partial stats for t rows: each (wave,mf) covers one 4-row group x 64 cols
    if (m0 < TROWS) {
        #pragma unroll
        for (int mf = 0; mf < 2; ++mf) {
            float s = 0.f, sq = 0.f;
            #pragma unroll
            for (int nf = 0; nf < 4; ++nf)
                #pragma unroll
                for (int i = 0; i < 4; ++i) {
                    float v = acc[mf][nf][i];
                    s += v; sq += v * v;
                }
            #pragma unroll
            for (int m = 1; m <= 8; m <<= 1) {
                s  += __shfl_xor(s, m);
                sq += __shfl_xor(sq, m);
            }
            if (rl == 0) {
                int grp = (m0 + wm * 32 + mf * 16 + kg * 4) >> 2;
                atomicAdd(&gnstat[(b * 64 + grp) * 2],     s);
                atomicAdd(&gnstat[(b * 64 + grp) * 2 + 1], sq);
            }
        }
    }
}

// ---------------------------------------------------------------- tkn2: normalize + affine + relu + transpose
__global__ __launch_bounds__(256) void tkn2_kernel(
    const short* __restrict__ tvb, const float* __restrict__ gnstat,
    const float* __restrict__ gn_g, const float* __restrict__ gn_b,
    short* __restrict__ tn)
{
    __shared__ short ts[64][72];
    __shared__ float sc[64], sh[64];
    int b4r = blockIdx.x;
    int b = b4r >> 2, r = b4r & 3;
    int hw0 = blockIdx.y * 64;
    int tid = threadIdx.x;
    if (tid < 64) {
        float s   = gnstat[(b * 64 + tid) * 2];
        float sq  = gnstat[(b * 64 + tid) * 2 + 1];
        float mu  = s * (1.f / 4096.f);
        float var = sq * (1.f / 4096.f) - mu * mu;
        float inv = rsqrtf(var + 1e-5f);
        int ch = tid * 4 + r;
        float g = gn_g[ch], bb = gn_b[ch];
        sc[tid] = inv * g;
        sh[tid] = bb - mu * inv * g;
    }
    #pragma unroll
    for (int l = 0; l < 16; ++l) {
        int flat = l * 256 + tid;
        int c = flat >> 6, hw = flat & 63;
        ts[c][hw] = tvb[((size_t)b * MROWS + c * 4 + r) * HW + hw0 + hw];
    }
    __syncthreads();
    #pragma unroll
    for (int l = 0; l < 2; ++l) {
        int u = l * 256 + tid;
        int hw = u >> 3, c0 = (u & 7) * 8;
        bf16x8 v;
        #pragma unroll
        for (int j = 0; j < 8; ++j) {
            float f = bf2f((unsigned short)ts[c0 + j][hw]);
            f = fmaxf(f * sc[c0 + j] + sh[c0 + j], 0.f);
            v[j] = f2bf(f);
        }
        *(bf16x8*)(tn + ((size_t)b4r * HW + hw0 + hw) * C2K + c0) = v;
    }
}

// ---------------------------------------------------------------- wmap v3b: MFMA GEMM, bf16 out, coalesced epilogue
// wmapB[b4r][o][hw] = bf16( c2bp[o] + sum_c c2wb[o][c] * tn[b4r][hw][c] ), o < 392 only
__global__ __launch_bounds__(256) void wmap3_kernel(
    const short* __restrict__ c2wb, const short* __restrict__ tn,
    const float* __restrict__ c2bp, short* __restrict__ wmapB)
{
    __shared__ short smem[64 * 64 + 128 * 64];   // 24 KB
    short* As = smem;            // [64][64]
    short* Bs = smem + 64 * 64;  // [128][64]
    short* Ps = smem;            // [64][136] = 17 KB, aliases after barrier
    int n0  = blockIdx.x * 128;
    int m0  = blockIdx.y * 64;
    int b4r = blockIdx.z;
    int tid = threadIdx.x;
    int lane = tid & 63, wv = tid >> 6;
    int wm = wv & 1, wn = wv >> 1;
    int rl = lane & 15, kg = lane >> 4;
    const short* Bb = tn + ((size_t)b4r * HW + n0) * C2K;

    #pragma unroll
    for (int l = 0; l < 2; ++l) {
        int c = l * 256 + tid;
        int row = c >> 3, kc = c & 7;
        int kcs = kc ^ (row & 7);
        __builtin_amdgcn_global_load_lds(
            (const AS1 void*)(c2wb + (size_t)(m0 + row) * C2K + kcs * 8),
            (AS3 void*)(As + (l * 256 + wv * 64) * 8), 16, 0, 0);
    }
    #pragma unroll
    for (int l = 0; l < 4; ++l) {
        int c = l * 256 + tid;
        int row = c >> 3, kc = c & 7;
        int kcs = kc ^ (row & 7);
        __builtin_amdgcn_global_load_lds(
            (const AS1 void*)(Bb + (size_t)row * C2K + kcs * 8),
            (AS3 void*)(Bs + (l * 256 + wv * 64) * 8), 16, 0, 0);
    }
    __syncthreads();

    f32x4 acc[2][4] = {};
    #pragma unroll
    for (int ks = 0; ks < 2; ++ks) {
        bf16x8 af[2], bfr[4];
        #pragma unroll
        for (int mf = 0; mf < 2; ++mf) {
            int row = wm * 32 + mf * 16 + rl;
            af[mf] = *(const bf16x8*)(As + row * 64 + ((ks * 4 + kg) ^ (row & 7)) * 8);
        }
        #pragma unroll
        for (int nf = 0; nf < 4; ++nf) {
            int row = wn * 64 + nf * 16 + rl;
            bfr[nf] = *(const bf16x8*)(Bs + row * 64 + ((ks * 4 + kg) ^ (row & 7)) * 8);
        }
        #pragma unroll
        for (int mf = 0; mf < 2; ++mf)
            #pragma unroll
            for (int nf = 0; nf < 4; ++nf)
                acc[mf][nf] = __builtin_amdgcn_mfma_f32_16x16x32_bf16(af[mf], bfr[nf], acc[mf][nf], 0, 0, 0);
    }
    __syncthreads();   // frag reads done -> reuse smem as Ps

    // repack: bias + bf16 into LDS [64][136]
    #pragma unroll
    for (int mf = 0; mf < 2; ++mf) {
        int rowl = wm * 32 + mf * 16 + kg * 4;
        float bi[4];
        #pragma unroll
        for (int i = 0; i < 4; ++i) bi[i] = c2bp[m0 + rowl + i];
        #pragma unroll
        for (int nf = 0; nf < 4; ++nf) {
            int col = wn * 64 + nf * 16 + rl;
            #pragma unroll
            for (int i = 0; i < 4; ++i)
                Ps[(rowl + i) * 136 + col] = f2bf(acc[mf][nf][i] + bi[i]);
        }
    }
    __syncthreads();

    // coalesced store: thread -> (row = tid>>2, 4 x 16B segments), skip pad rows
    int row = tid >> 2, segl = tid & 3;
    if (m0 + row < WMAP_O) {
        short* dst = wmapB + (size_t)b4r * WMAP_OP * HW + (size_t)(m0 + row) * HW + n0;
        #pragma unroll
        for (int s2 = 0; s2 < 4; ++s2) {
            int col = segl * 8 + s2 * 32;
            *(bf16x8*)(dst + col) = *(const bf16x8*)(Ps + row * 136 + col);
        }
    }
}

// ---------------------------------------------------------------- aggregation v6
// grid: (256 bgr, 4 h-strips, 2 c-halves); block: 8 ch x 8 h x 32 w
// lane map keeps weight sharing: w0q=tid&7, hb=(tid>>3)&1, cc4=(tid>>4)&3, cq=wave
// each lane owns 2 channels (cc4*2+c2); vt 21.1 KB -> ~5 blocks/CU
__global__ __launch_bounds__(256, 5) void agg6_kernel(
    const short* __restrict__ tvb, const short* __restrict__ wmapB,
    float* __restrict__ out)
{
    __shared__ float vt[8][15][44];   // 21.1 KB
    int bx = blockIdx.x;              // b*32 + g*4 + r
    int b = bx >> 5;
    int g = (bx >> 2) & 7;
    int r = bx & 3;
    int h0   = blockIdx.y * 8;
    int half = blockIdx.z;
    int tid  = threadIdx.x;
    int w0q = tid & 7, hb = (tid >> 3) & 1, cc4 = (tid >> 4) & 3, cq = tid >> 6;
    int hl = cq * 2 + hb;             // local h 0..7
    int h = h0 + hl, w0 = w0q * 4;

    int A, Bc, Cc;
    if      (r == 0) { A = 0;  Bc = 7;  Cc = 1;  }
    else if (r == 1) { A = 6;  Bc = -1; Cc = 7;  }
    else if (r == 2) { A = 48; Bc = -7; Cc = -1; }
    else             { A = 42; Bc = 1;  Cc = -7; }

    const short* vpb = tvb + ((size_t)b * MROWS + TROWS) * HW;
    // edge quads (cols 0..3, 36..43) always out of image -> zero
    for (int e = tid; e < 8 * 15 * 3; e += 256) {
        int cc  = e / 45;
        int rem = e - cc * 45;
        int row = rem / 3, q = rem - row * 3;
        int col = (q == 0) ? 0 : (36 + (q - 1) * 4);
        *(float4*)(&vt[cc][row][col]) = make_float4(0.f, 0.f, 0.f, 0.f);
    }
    // interior quads: cols 4..35 <-> gw 0..31 (aligned ushort4)
    for (int f = tid; f < 8 * 15 * 8; f += 256) {
        int cc  = f / 120;
        int rem = f - cc * 120;
        int row = rem >> 3, q = rem & 7;
        int gh = h0 - 3 + row;
        float4 v4 = make_float4(0.f, 0.f, 0.f, 0.f);
        if (gh >= 0 && gh < HH) {
            int ch = (g * GC + half * 8 + cc) * 4 + r;
            ushort4 u = *(const ushort4*)(vpb + (size_t)ch * HW + gh * WWID + q * 4);
            v4 = make_float4(bf2f(u.x), bf2f(u.y), bf2f(u.z), bf2f(u.w));
        }
        *(float4*)(&vt[cc][row][4 + q * 4]) = v4;
    }
    __syncthreads();

    const short* wmb = wmapB + ((size_t)(b * 4 + r) * WMAP_OP + g * 49) * HW + h * WWID + w0;
    float acc[2][4] = {};
    #pragma unroll
    for (int di = 0; di < 7; ++di) {
        float wrf[7][4];
        #pragma unroll
        for (int dj = 0; dj < 7; ++dj) {
            int porig = A + Bc * di + Cc * dj;
            ushort4 wv = *(const ushort4*)(wmb + (size_t)porig * HW);
            wrf[dj][0] = bf2f(wv.x); wrf[dj][1] = bf2f(wv.y);
            wrf[dj][2] = bf2f(wv.z); wrf[dj][3] = bf2f(wv.w);
        }
        #pragma unroll
        for (int c2 = 0; c2 < 2; ++c2) {
            int hc = cc4 * 2 + c2;
            const float* rp = &vt[hc][hl + di][w0];
            float4 q0 = *(const float4*)(rp);
            float4 q1 = *(const float4*)(rp + 4);
            float4 q2 = *(const float4*)(rp + 8);
            float win[12] = {q0.x, q0.y, q0.z, q0.w,
                             q1.x, q1.y, q1.z, q1.w,
                             q2.x, q2.y, q2.z, q2.w};
            #pragma unroll
            for (int dj = 0; dj < 7; ++dj)
                #pragma unroll
                for (int px = 0; px < 4; ++px)
                    acc[c2][px] += wrf[dj][px] * win[px + dj + 1];
        }
    }
    #pragma unroll
    for (int c2 = 0; c2 < 2; ++c2) {
        int ch = (g * GC + half * 8 + cc4 * 2 + c2) * 4 + r;
        float4 o4 = make_float4(acc[c2][0], acc[c2][1], acc[c2][2], acc[c2][3]);
        *(float4*)(out + ((size_t)b * 512 + ch) * HW + h * WWID + w0) = o4;
    }
}

// ---------------------------------------------------------------- launch
extern "C" void kernel_launch(void* const* d_in, const int* in_sizes, int n_in,
                              void* d_out, int out_size, void* d_ws, size_t ws_size,
                              hipStream_t stream)
{
    const float* x    = (const float*)d_in[0];
    const float* v_w  = (const float*)d_in[1];
    const float* c1_w = (const float*)d_in[2];
    const float* gn_g = (const float*)d_in[3];
    const float* gn_b = (const float*)d_in[4];
    const float* c2_w = (const float*)d_in[5];
    const float* c2_b = (const float*)d_in[6];
    float* out = (float*)d_out;

    // workspace layout (XT aliases wmapB; XT dead before wmapB written)
    char* p = (char*)d_ws;
    short* Wb     = (short*)p;           p += (size_t)MROWS * KDIM * 2;        //  0.79 MB
    short* tvb    = (short*)p;           p += (size_t)BB * MROWS * HW * 2;     // 12.6 MB
    short* wmapB  = (short*)p;           p += (size_t)32 * WMAP_OP * HW * 2;   // 29.4 MB
    short* XT     = (short*)wmapB;                                             //  8.4 MB (aliased)
    short* tn     = (short*)p;           p += (size_t)32 * HW * C2K * 2;       //  4.2 MB
    short* c2wb   = (short*)p;           p += (size_t)WMAP_OP * C2K * 2;       // 57 KB
    float* c2bp   = (float*)p;           p += (size_t)WMAP_OP * 4;
    float* gnstat = (float*)p;           p += (size_t)512 * 2 * 4;             //  4 KB

    prep_kernel     <<<2673, 256, 0, stream>>>(x, v_w, c1_w, c2_w, c2_b, XT, Wb, c2wb, c2bp, gnstat);
    gemm_mfma_kernel<<<dim3(HW / GBN, MROWS / GBM, BB), 256, 0, stream>>>(Wb, XT, tvb, gnstat);
    tkn2_kernel     <<<dim3(32, 16), 256, 0, stream>>>(tvb, gnstat, gn_g, gn_b, tn);
    wmap3_kernel    <<<dim3(HW / 128, WMAP_OP / 64, 32), 256, 0, stream>>>(c2wb, tn, c2bp, wmapB);
    agg6_kernel     <<<dim3(BB * NG * 4, 4, 2), 256, 0, stream>>>(tvb, wmapB, out);
}